// Round 1
// baseline (283.177 us; speedup 1.0000x reference)
//
#include <hip/hip_runtime.h>

// RoiPooling via integral image, channel-last S in workspace.
// S layout: S[y][x][c], y,x in [0,257), c in [0,512). S[y][x][c] = sum fm[c, :y, :x].
// ws usage: 257*257*512*4 bytes = 135,268,352 (~129 MB).

#define CHN   512
#define HDIM  256
#define WDIM  256
#define SP    257   // padded spatial dim of S

// ---------------- Kernel Z: zero row 0 and column 0 of S -------------------
__global__ __launch_bounds__(256) void zeroK(float* __restrict__ S) {
    int gid = blockIdx.x * 256 + threadIdx.x;
    const int half = SP * CHN;            // 257*512 = 131584
    if (gid < half) {
        // row y=0: address (0*SP + x)*CHN + c == gid
        S[gid] = 0.0f;
    } else {
        int g2 = gid - half;
        if (g2 < half) {
            int y = g2 >> 9;              // /512
            int c = g2 & 511;
            S[((size_t)y * SP) * CHN + c] = 0.0f;  // col x=0
        }
    }
}

// ---------------- Kernel A: row prefix scan (fp64 acc) + transpose to S ----
// Block: 256 threads, handles one y and 32 channels. LDS tile 32x257 floats.
// Writes S[(y+1)][(x+1)][c0+cil] = inclusive prefix of fm[c][y][0..x].
__global__ __launch_bounds__(256) void rowScanK(const float* __restrict__ fm,
                                               float* __restrict__ S) {
    __shared__ float tile[32][SP];
    __shared__ double part[32][9];
    const int t  = threadIdx.x;
    const int y  = blockIdx.x;            // 0..255
    const int c0 = blockIdx.y * 32;       // 0,32,...,480

    // Load 32 channel-rows of 256 floats via float4 (4 rows per iter, 8 iters).
    {
        const int xr = (t & 63) * 4;
        const int cb = t >> 6;            // 0..3
        #pragma unroll
        for (int i = 0; i < 8; ++i) {
            const int c = i * 4 + cb;
            const float4 v = *(const float4*)(fm + ((size_t)(c0 + c) << 16)
                                                 + ((size_t)y << 8) + xr);
            tile[c][xr]     = v.x;
            tile[c][xr + 1] = v.y;
            tile[c][xr + 2] = v.z;
            tile[c][xr + 3] = v.w;
        }
    }
    __syncthreads();

    const int r = t & 31;                 // channel within tile
    const int s = t >> 5;                 // segment 0..7 (32 elements each)
    // Phase 1: per-segment fp64 sums
    {
        double a = 0.0;
        #pragma unroll 8
        for (int i = 0; i < 32; ++i) a += (double)tile[r][s * 32 + i];
        part[r][s] = a;
    }
    __syncthreads();
    // Phase 2: exclusive scan of the 8 segment sums per row
    if (t < 32) {
        double o = 0.0;
        #pragma unroll
        for (int ss = 0; ss < 8; ++ss) {
            double p = part[t][ss];
            part[t][ss] = o;
            o += p;
        }
    }
    __syncthreads();
    // Phase 3: re-scan segment with offset, write fp32 prefix back to tile
    {
        double acc = part[r][s];
        #pragma unroll 8
        for (int i = 0; i < 32; ++i) {
            acc += (double)tile[r][s * 32 + i];
            tile[r][s * 32 + i] = (float)acc;
        }
    }
    __syncthreads();
    // Phase 4: write transposed into S (channel-last). 32x256 elems, 32 iters.
    {
        #pragma unroll 4
        for (int it = 0; it < 32; ++it) {
            const int j   = it * 256 + t;
            const int cil = j & 31;
            const int x   = j >> 5;
            S[(((size_t)(y + 1)) * SP + (x + 1)) * CHN + (c0 + cil)] = tile[cil][x];
        }
    }
}

// ---------------- Kernel B: column scan (in place, fp64 acc) ---------------
// Thread per (x,c): consecutive threads -> consecutive c (coalesced).
__global__ __launch_bounds__(256) void colScanK(float* __restrict__ S) {
    const int g = blockIdx.x * 256 + threadIdx.x;  // 0 .. 256*512-1
    const int c = g & 511;
    const int x = (g >> 9) + 1;                    // 1..256
    size_t idx = ((size_t)SP + x) * CHN + c;       // y=1
    double acc = 0.0;
    #pragma unroll 4
    for (int yy = 1; yy <= HDIM; ++yy) {
        const float v = S[idx];
        acc += (double)v;
        S[idx] = (float)acc;
        idx += (size_t)SP * CHN;
    }
}

// ---------------- Kernel C: 4-corner gather + normalize --------------------
__global__ __launch_bounds__(256) void gatherK(const float* __restrict__ S,
                                              const float* __restrict__ roi,
                                              float* __restrict__ out,
                                              float* __restrict__ maskOut,
                                              int N) {
    const int b = blockIdx.x;             // 0 .. 4N-1, patch-major
    const int n = b % N;
    const int p = b / N;

    const float xmin = roi[4 * n + 0];
    const float ymin = roi[4 * n + 1];
    const float xmax = roi[4 * n + 2];
    const float ymax = roi[4 * n + 3];

    // pe = 2 (patch_num = 4). Replicate np fp32 op order exactly (no fma).
    const float ixf = (float)(p & 1);
    const float iyf = (float)(p >> 1);
    const float wsv = __fdiv_rn(__fsub_rn(xmax, xmin), 2.0f);
    const float hsv = __fdiv_rn(__fsub_rn(ymax, ymin), 2.0f);
    const float ax  = __fadd_rn(xmin, __fmul_rn(ixf, wsv));
    const float ay  = __fadd_rn(ymin, __fmul_rn(iyf, hsv));

    // clampi = clip(round(v), 0, W-1); np.round = half-to-even = rintf
    const float lim = (float)(WDIM - 1);
    float f;
    f = fminf(fmaxf(rintf(ax), 0.0f), lim);                     const int x0 = (int)f;
    f = fminf(fmaxf(rintf(__fadd_rn(ax, wsv)), 0.0f), lim);     const int x1 = (int)f;
    f = fminf(fmaxf(rintf(ay), 0.0f), lim);                     const int y0 = (int)f;
    f = fminf(fmaxf(rintf(__fadd_rn(ay, hsv)), 0.0f), lim);     const int y1 = (int)f;

    const int cw = x1 - x0;
    const int ch = y1 - y0;
    const int maskv = (cw >= 1 && ch >= 1) ? 1 : 0;
    int areai = cw * ch; if (areai < 1) areai = 1;
    const float areaf = (float)areai;
    const float maskf = (float)maskv;

    const float* p11 = S + ((size_t)y1 * SP + x1) * CHN;
    const float* p01 = S + ((size_t)y0 * SP + x1) * CHN;
    const float* p10 = S + ((size_t)y1 * SP + x0) * CHN;
    const float* p00 = S + ((size_t)y0 * SP + x0) * CHN;
    float* ob = out + (size_t)b * CHN;

    const int t = threadIdx.x;
    #pragma unroll
    for (int k = 0; k < 2; ++k) {
        const int c = t + k * 256;
        // reference op order: ((S11 - S01) - S10) + S00, then /area, then *mask
        float v = ((p11[c] - p01[c]) - p10[c]) + p00[c];
        v = __fdiv_rn(v, areaf);
        ob[c] = v * maskf;
    }
    if (t == 0) maskOut[b] = maskf;
}

// ---------------------------------------------------------------------------
extern "C" void kernel_launch(void* const* d_in, const int* in_sizes, int n_in,
                              void* d_out, int out_size, void* d_ws, size_t ws_size,
                              hipStream_t stream) {
    const float* fm  = (const float*)d_in[0];
    const float* roi = (const float*)d_in[1];
    // d_in[2] = patch_num (always 4 in this problem); pe=2 hardcoded in gatherK.

    const int N = in_sizes[1] / 4;     // 4096
    const int B = 4 * N;               // 16384

    float* S       = (float*)d_ws;                       // 257*257*512 floats
    float* out     = (float*)d_out;                      // B*512 pooled
    float* maskOut = out + (size_t)B * CHN;              // B mask values

    // zero border (ws is poisoned every call)
    zeroK<<<(2 * SP * CHN + 255) / 256, 256, 0, stream>>>(S);

    // row prefix scan + transpose: grid (y=256, ctile=16)
    dim3 gA(HDIM, CHN / 32);
    rowScanK<<<gA, 256, 0, stream>>>(fm, S);

    // column scan: 256*512 threads
    colScanK<<<(WDIM * CHN) / 256, 256, 0, stream>>>(S);

    // gather: one block per output region
    gatherK<<<B, 256, 0, stream>>>(S, roi, out, maskOut, N);
}